// Round 2
// baseline (293.162 us; speedup 1.0000x reference)
//
#include <hip/hip_runtime.h>

typedef float v2f __attribute__((ext_vector_type(2)));

#define KS    11
#define HH    512
#define WW    512
#define OUTD  502          // HH - KS + 1
#define OH    34           // output rows per band
#define ROWS  44           // OH + KS - 1 rows staged (4 groups of 11)
#define NBR   15           // ceil(502/34) row bands
#define NBC   2            // column tiles
#define TC    256          // output cols per block
#define SG    266          // staged cols per block (TC + KS - 1)
#define NIMG  96           // N*C

// Streaming separable SSIM, v2:
//  - 1 output column per thread (55-float accumulator ring -> fits VGPRs,
//    no v_accvgpr round-trips; r1 showed 110-float ring was AGPR-offloaded)
//  - LDS staged as interleaved (x,y) float2: mu and sigma moments convolve
//    as packed pairs -> v_pk_fma_f32 (dual-fp32), xy moment stays scalar
//  - block = (img, 44-row band, 256-col tile); double-buffered row staging,
//    one barrier per row; vertical conv via 11 rotating register slots.
__global__ __launch_bounds__(256, 3)
void ssim_main(const float* __restrict__ xg, const float* __restrict__ yg,
               const float* __restrict__ win, double* __restrict__ acc_out)
{
    __shared__ v2f buf[2][SG];      // (x,y) pairs per staged column
    __shared__ float wsums[4];

    const int tid = threadIdx.x;
    int bb = blockIdx.x;
    const int img   = bb % NIMG;  bb /= NIMG;
    const int band  = bb % NBR;   bb /= NBR;
    const int ctile = bb;                       // 0..NBC-1
    const int row0  = band * OH;
    const int cb    = ctile * TC;

    // 1D gaussian from row sums of the rank-1, normalized 2D window.
    // win is wave-uniform -> compiler scalarizes these loads.
    float g[KS];
    #pragma unroll
    for (int i = 0; i < KS; i++) {
        float s = 0.f;
        #pragma unroll
        for (int j = 0; j < KS; j++) s += win[i * KS + j];
        g[i] = s;
    }

    const float* xi = xg + (size_t)img * HH * WW;
    const float* yi = yg + (size_t)img * HH * WW;

    // rotating vertical accumulators: packed (mu_x,mu_y), (Sxx,Syy), scalar Sxy
    v2f   aMu[KS], aSq[KS];
    float aXy[KS];
    #pragma unroll
    for (int s = 0; s < KS; s++) {
        aMu[s] = (v2f)0.f; aSq[s] = (v2f)0.f; aXy[s] = 0.f;
    }

    float ssum = 0.f;
    const float C1 = 0.0001f;   // (0.01)^2
    const float C2 = 0.0009f;   // (0.03)^2

    // staging: slot tid always; slot TC+tid for tid<10 (zero past image edge)
    float px0, py0, px1, py1;
    auto load_row = [&](int r, float& x0, float& y0, float& x1, float& y1) {
        int gr = row0 + r; if (gr > HH - 1) gr = HH - 1;
        const size_t base = (size_t)gr * WW;
        const int gc0 = cb + tid;              // always < WW
        x0 = xi[base + gc0]; y0 = yi[base + gc0];
        x1 = 0.f; y1 = 0.f;
        if (tid < SG - TC) {
            const int gc1 = cb + TC + tid;
            if (gc1 < WW) { x1 = xi[base + gc1]; y1 = yi[base + gc1]; }
        }
    };
    auto store_row = [&](int bsel, float x0, float y0, float x1, float y1) {
        v2f v; v.x = x0; v.y = y0;
        buf[bsel][tid] = v;
        if (tid < SG - TC) { v2f w; w.x = x1; w.y = y1; buf[bsel][TC + tid] = w; }
    };

    // prologue: row 0 -> buf0; prefetch row 1 into regs
    load_row(0, px0, py0, px1, py1);
    store_row(0, px0, py0, px1, py1);
    load_row(1, px0, py0, px1, py1);
    __syncthreads();

    #pragma unroll 1
    for (int rb = 0; rb < ROWS / KS; rb++) {
        #pragma unroll
        for (int rr = 0; rr < KS; rr++) {
            const int r = rb * KS + rr;
            const v2f* bufr = buf[r & 1];

            // write prefetched row r+1; prefetch row r+2
            if (r + 1 < ROWS) store_row((r + 1) & 1, px0, py0, px1, py1);
            if (r + 2 < ROWS) load_row(r + 2, px0, py0, px1, py1);

            // horizontal 11-tap conv (packed mu/sq, scalar xy)
            v2f hMu = (v2f)0.f, hSq = (v2f)0.f;
            float hXy = 0.f;
            #pragma unroll
            for (int j = 0; j < KS; j++) {
                const v2f v = bufr[tid + j];           // ds_read_b64
                v2f gg; gg.x = g[j]; gg.y = g[j];
                hMu = __builtin_elementwise_fma(gg, v, hMu);
                const v2f sq = v * v;                   // v_pk_mul_f32
                hSq = __builtin_elementwise_fma(gg, sq, hSq);
                hXy = fmaf(g[j], v.x * v.y, hXy);
            }

            // vertical accumulate into rotating slots (compile-time slot idx)
            #pragma unroll
            for (int i = 0; i < KS; i++) {
                const int slot = (rr - i + KS) % KS;
                v2f gg; gg.x = g[i]; gg.y = g[i];
                aMu[slot] = __builtin_elementwise_fma(gg, hMu, aMu[slot]);
                aSq[slot] = __builtin_elementwise_fma(gg, hSq, aSq[slot]);
                aXy[slot] = fmaf(g[i], hXy, aXy[slot]);
            }

            // emit completed output row jloc = r-10 (slot (rr+1)%11)
            const int es   = (rr + 1) % KS;
            const int jloc = r - (KS - 1);
            if (jloc >= 0 && (row0 + jloc) < OUTD && (cb + tid) < OUTD) {
                const float mx  = aMu[es].x, my  = aMu[es].y;
                const float Sxx = aSq[es].x, Syy = aSq[es].y, Sxy = aXy[es];
                const float mxx = mx * mx, myy = my * my, mxy = mx * my;
                const float sxx = Sxx - mxx, syy = Syy - myy, sxy = Sxy - mxy;
                const float num = (2.f * mxy + C1) * (2.f * sxy + C2);
                const float den = (mxx + myy + C1) * (sxx + syy + C2);
                float rc = __builtin_amdgcn_rcpf(den);
                rc = rc * fmaf(-den, rc, 2.0f);   // one NR step
                ssum = fmaf(num, rc, ssum);
            }
            // reset emitted slots every row (valid or not)
            aMu[es] = (v2f)0.f; aSq[es] = (v2f)0.f; aXy[es] = 0.f;

            __syncthreads();
        }
    }

    // block reduction: wave shuffle, then cross-wave via LDS
    #pragma unroll
    for (int off = 32; off > 0; off >>= 1)
        ssum += __shfl_down(ssum, off);
    const int wave = tid >> 6;
    if ((tid & 63) == 0) wsums[wave] = ssum;
    __syncthreads();
    if (tid == 0) {
        float s = wsums[0] + wsums[1] + wsums[2] + wsums[3];
        atomicAdd(acc_out, (double)s);
    }
}

__global__ void ssim_finalize(const double* __restrict__ acc, float* __restrict__ out)
{
    // total outputs: 96 * 502 * 502 = 24,192,384
    out[0] = (float)(acc[0] * (1.0 / 24192384.0));
}

extern "C" void kernel_launch(void* const* d_in, const int* in_sizes, int n_in,
                              void* d_out, int out_size, void* d_ws, size_t ws_size,
                              hipStream_t stream)
{
    const float* x   = (const float*)d_in[0];
    const float* y   = (const float*)d_in[1];
    const float* win = (const float*)d_in[2];
    float* out = (float*)d_out;
    double* acc = (double*)d_ws;

    hipMemsetAsync(acc, 0, sizeof(double), stream);
    ssim_main<<<dim3(NIMG * NBR * NBC), dim3(256), 0, stream>>>(x, y, win, acc);
    ssim_finalize<<<dim3(1), dim3(1), 0, stream>>>(acc, out);
}

// Round 3
// 285.242 us; speedup vs baseline: 1.0278x; 1.0278x over previous
//
#include <hip/hip_runtime.h>

typedef float v2f __attribute__((ext_vector_type(2)));

#define KS    11
#define HH    512
#define WW    512
#define OUTD  502          // HH - KS + 1
#define OH    34           // output rows per band
#define GR    11           // rows staged per barrier group
#define NG    4            // groups per band -> ROWS = 44
#define NBR   15           // row bands
#define NBC   2            // column tiles
#define TC    256          // output cols per block
#define CH    67           // float4 chunks per staged row (covers 268 cols)
#define SGL   268          // staged cols (266 needed, 268 loaded)
#define NIMG  96
#define ITEMS (GR * CH)    // 737 staging items per group

// Deterministic dual-fp32: r2 counters implied ~227 VALU instr/row (packed
// math scalarized). Force VOP3P with inline asm.
__device__ __forceinline__ v2f pk_fma(v2f a, v2f b, v2f c) {
    v2f d;
    asm("v_pk_fma_f32 %0, %1, %2, %3" : "=v"(d) : "v"(a), "v"(b), "v"(c));
    return d;
}
__device__ __forceinline__ v2f pk_mul(v2f a, v2f b) {
    v2f d;
    asm("v_pk_mul_f32 %0, %1, %2" : "=v"(d) : "v"(a), "v"(b));
    return d;
}

// Streaming separable SSIM, v3:
//  - 1 output col/thread, 55-float rotating ring (fits VGPRs, r1 lesson)
//  - 11 rows staged per barrier group: 8 barriers/block instead of 44
//    (r2 lesson: per-row barriers cost ~40% stall)
//  - register prefetch of group g+1/g+2 overlaps compute of group g
//  - packed (x,y) / (Sxx,Syy) moments via explicit v_pk_fma_f32
__global__ __launch_bounds__(256, 3)
void ssim_main(const float* __restrict__ xg, const float* __restrict__ yg,
               const float* __restrict__ win, double* __restrict__ acc_out)
{
    __shared__ v2f buf[GR][SGL];     // (x,y) pairs, one 11-row group
    __shared__ float wsums[4];

    const int tid = threadIdx.x;
    int bb = blockIdx.x;
    const int img  = bb % NIMG;  bb /= NIMG;
    const int band = bb % NBR;   bb /= NBR;
    const int cb   = bb * TC;
    const int row0 = band * OH;

    // 1D gaussian = row sums of the rank-1 normalized 2D window.
    // Symmetric: keep 6 unique broadcast pairs.
    v2f g2[6];
    #pragma unroll
    for (int i = 0; i < 6; i++) {
        float s = 0.f;
        #pragma unroll
        for (int j = 0; j < KS; j++) s += win[i * KS + j];
        v2f p; p.x = s; p.y = s; g2[i] = p;
    }

    const float* xi = xg + (size_t)img * (HH * WW);
    const float* yi = yg + (size_t)img * (HH * WW);

    float4 pfx[3], pfy[3];
    auto prefetch = [&](int g) {
        #pragma unroll
        for (int it = 0; it < 3; it++) {
            const int idx = tid + 256 * it;
            if (it < 2 || idx < ITEMS) {
                int i = idx / CH, k = idx - i * CH;
                int gr = row0 + g * GR + i; if (gr > HH - 1) gr = HH - 1;
                int gc = cb + 4 * k;        if (gc > WW - 4) gc = WW - 4;
                const size_t base = (size_t)gr * WW + gc;
                pfx[it] = *(const float4*)(xi + base);
                pfy[it] = *(const float4*)(yi + base);
            }
        }
    };
    auto store_s = [&]() {
        #pragma unroll
        for (int it = 0; it < 3; it++) {
            const int idx = tid + 256 * it;
            if (it < 2 || idx < ITEMS) {
                int i = idx / CH, k = idx - i * CH;
                const float4 xv = pfx[it], yv = pfy[it];
                float4 a; a.x = xv.x; a.y = yv.x; a.z = xv.y; a.w = yv.y;
                float4 b; b.x = xv.z; b.y = yv.z; b.z = xv.w; b.w = yv.w;
                *(float4*)&buf[i][4 * k]     = a;   // ds_write_b128
                *(float4*)&buf[i][4 * k + 2] = b;
            }
        }
    };

    // rotating vertical accumulators: packed (mu_x,mu_y), (Sxx,Syy), scalar Sxy
    v2f aMu[KS], aSq[KS]; float aXy[KS];
    #pragma unroll
    for (int s = 0; s < KS; s++) { aMu[s] = (v2f)0.f; aSq[s] = (v2f)0.f; aXy[s] = 0.f; }

    float ssum = 0.f;
    const float C1 = 0.0001f;   // (0.01)^2
    const float C2 = 0.0009f;   // (0.03)^2
    const bool colvalid = (cb + tid) < OUTD;

    prefetch(0); store_s(); prefetch(1);
    __syncthreads();

    #pragma unroll 1
    for (int g = 0; g < NG; g++) {
        #pragma unroll
        for (int rr = 0; rr < GR; rr++) {
            const v2f* rowp = &buf[rr][tid];

            // horizontal 11-tap conv (packed mu/sq, scalar xy)
            v2f hMu = (v2f)0.f, hSq = (v2f)0.f; float hXy = 0.f;
            #pragma unroll
            for (int j = 0; j < KS; j++) {
                const v2f gj = g2[j < 6 ? j : 10 - j];
                const v2f v = rowp[j];                 // ds_read_b64
                hMu = pk_fma(gj, v, hMu);
                hSq = pk_fma(gj, pk_mul(v, v), hSq);
                hXy = fmaf(gj.x, v.x * v.y, hXy);
            }

            // vertical accumulate into rotating slots (compile-time indices)
            #pragma unroll
            for (int i = 0; i < KS; i++) {
                const int slot = (rr - i + KS) % KS;
                const v2f gi = g2[i < 6 ? i : 10 - i];
                aMu[slot] = pk_fma(gi, hMu, aMu[slot]);
                aSq[slot] = pk_fma(gi, hSq, aSq[slot]);
                aXy[slot] = fmaf(gi.x, hXy, aXy[slot]);
            }

            // emit completed output row jloc = r-10 (slot (rr+1)%11)
            const int es   = (rr + 1) % KS;
            const int r    = g * GR + rr;
            const int jloc = r - (KS - 1);
            if (jloc >= 0 && (row0 + jloc) < OUTD && colvalid) {
                const float mx  = aMu[es].x, my  = aMu[es].y;
                const float Sxx = aSq[es].x, Syy = aSq[es].y, Sxy = aXy[es];
                const float mxx = mx * mx, myy = my * my, mxy = mx * my;
                const float sxx = Sxx - mxx, syy = Syy - myy, sxy = Sxy - mxy;
                const float num = (2.f * mxy + C1) * (2.f * sxy + C2);
                const float den = (mxx + myy + C1) * (sxx + syy + C2);
                float rc = __builtin_amdgcn_rcpf(den);
                rc = rc * fmaf(-den, rc, 2.0f);   // one NR step
                ssum = fmaf(num, rc, ssum);
            }
            // reset emitted slots for reuse
            aMu[es] = (v2f)0.f; aSq[es] = (v2f)0.f; aXy[es] = 0.f;
        }

        __syncthreads();                 // all waves done reading buf
        if (g < NG - 1) {
            store_s();                   // group g+1 regs -> LDS
            __syncthreads();             // buf ready
            if (g < NG - 2) prefetch(g + 2);   // overlap next loads w/ compute
        }
    }

    // block reduction: wave shuffle, then cross-wave via LDS
    #pragma unroll
    for (int off = 32; off > 0; off >>= 1)
        ssum += __shfl_down(ssum, off);
    const int wave = tid >> 6;
    if ((tid & 63) == 0) wsums[wave] = ssum;
    __syncthreads();
    if (tid == 0) {
        float s = wsums[0] + wsums[1] + wsums[2] + wsums[3];
        atomicAdd(acc_out, (double)s);
    }
}

__global__ void ssim_finalize(const double* __restrict__ acc, float* __restrict__ out)
{
    // total outputs: 96 * 502 * 502 = 24,192,384
    out[0] = (float)(acc[0] * (1.0 / 24192384.0));
}

extern "C" void kernel_launch(void* const* d_in, const int* in_sizes, int n_in,
                              void* d_out, int out_size, void* d_ws, size_t ws_size,
                              hipStream_t stream)
{
    const float* x   = (const float*)d_in[0];
    const float* y   = (const float*)d_in[1];
    const float* win = (const float*)d_in[2];
    float* out = (float*)d_out;
    double* acc = (double*)d_ws;

    hipMemsetAsync(acc, 0, sizeof(double), stream);
    ssim_main<<<dim3(NIMG * NBR * NBC), dim3(256), 0, stream>>>(x, y, win, acc);
    ssim_finalize<<<dim3(1), dim3(1), 0, stream>>>(acc, out);
}